// Round 3
// baseline (1807.287 us; speedup 1.0000x reference)
//
#include <hip/hip_runtime.h>

#define BATCH 32
#define DIM   3072
#define NTRAIN 100000
#define NBLK  256
#define JPB   391        /* ceil(100000/256) */
#define JT    16         /* j per subtile */
#define KC    512        /* k per chunk */
#define NCHUNK 6         /* DIM/KC */
#define WAVES 8
#define DPW   384        /* DIM/WAVES */
#define NTILE 12         /* DPW/32 */

/* LDS layout (bytes) */
#define TH_B   0u        /* [16][3072] bf16 swizzled, persists per subtile: 98304 B */
#define TL_B   98304u    /* 2 x [16][512] bf16 swizzled (double buffer):   32768 B */
#define ARED_B 98304u    /* alias TL0: [8][32][16] f32: 16384 B */
#define TSQ_B  114688u   /* alias TL1: [16] f32 */
#define LG_B   114752u   /* [32][17] f32: 2176 B */
#define CORR_B 116928u   /* [32] f32 */

typedef __bf16 bf16x8 __attribute__((ext_vector_type(8)));
typedef float  f32x4  __attribute__((ext_vector_type(4)));
typedef float  f32x16 __attribute__((ext_vector_type(16)));
typedef unsigned short u16;
typedef unsigned int   u32;

union F8 { u16 us[8]; u32 ui[4]; uint4 u4; bf16x8 bf; };

__device__ __forceinline__ u16   bft(float f){ return (u16)(__float_as_uint(f) >> 16); }
__device__ __forceinline__ float bfh(float f){ return __uint_as_float(__float_as_uint(f) & 0xFFFF0000u); }

/* swizzled byte offset inside a [16][3072] bf16 region (row stride 6144 B) */
__device__ __forceinline__ u32 offTH(u32 row, u32 kb){
    return row*6144u + (kb ^ ((row & 15u) << 4) ^ (((kb >> 6) & 3u) << 4));
}
/* swizzled byte offset inside a [16][512] bf16 region (row stride 1024 B) */
__device__ __forceinline__ u32 offTL(u32 row, u32 kb){
    return row*1024u + (kb ^ ((row & 15u) << 4) ^ (((kb >> 6) & 3u) << 4));
}

// ---------------- K0: split x into bf16 hi/lo ----------------
__global__ __launch_bounds__(256) void k0_split_x(
        const float* __restrict__ x, u16* __restrict__ xh, u16* __restrict__ xl) {
    int i = blockIdx.x * 256 + threadIdx.x;
    if (i >= BATCH * DIM) return;
    float f  = x[i];
    xh[i] = bft(f);
    xl[i] = bft(f - bfh(f));
}

// ---------------- fused: logits + online softmax + PV, one train pass ----------------
__global__ __launch_bounds__(512, 2) void fused_kernel(
        const float* __restrict__ train,
        const u16* __restrict__ xh, const u16* __restrict__ xl,
        const float* __restrict__ alphas, const int* __restrict__ tptr,
        float* __restrict__ partial,   // [NBLK][32][3072]
        float* __restrict__ m_arr,     // [NBLK][32]
        float* __restrict__ l_arr) {   // [NBLK][32]
    __shared__ __align__(16) char smem[131072];

    const int tid  = threadIdx.x;
    const int lane = tid & 63;
    const int w    = tid >> 6;        // wave 0..7
    const int l15  = lane & 15;
    const int q4   = lane >> 4;       // k-group for 16x16x32
    const int l31  = lane & 31;
    const int g32  = lane >> 5;       // k-group for 32x32x16
    const int bid  = blockIdx.x;

    const float ab = alphas[tptr[0]];
    const float s  = sqrtf(ab);
    const float om = 1.0f - ab;
    const float c1 = s / om;
    const float c2 = ab / (2.0f * om);

    const int jstart = bid * JPB;
    const int jlim   = min(jstart + JPB, NTRAIN);
    const int nsub   = (jlim - jstart + JT - 1) / JT;

    // staging mapping: 512 threads cover [16 rows][512 k] f32 per chunk
    const int srow = tid >> 5;   // 0..15
    const int sc   = tid & 31;   // 0..31

    f32x16 acc[NTILE];
#pragma unroll
    for (int t0 = 0; t0 < NTILE; ++t0)
#pragma unroll
        for (int r = 0; r < 16; ++r) acc[t0][r] = 0.0f;

    float m_run = -1e30f, l_run = 0.0f;

    for (int st = 0; st < nsub; ++st) {
        const int jbase = jstart + st * JT;
        __syncthreads();   // protect th region from previous phase C readers

        float tsqp = 0.0f;
        const int jg = min(jbase + srow, jlim - 1);
        const float* rbase = train + (size_t)jg * DIM + sc * 4;

        // convert + swizzled-write one float4 group (16 B) of chunk c, group i
        auto cvw = [&](float4 v, int c, int i) {
            u32 kbTH = (u32)(c * 1024 + i * 256 + sc * 8);
            u32 kbTL = (u32)(i * 256 + sc * 8);
            u32 h0 = (__float_as_uint(v.x) >> 16) | (__float_as_uint(v.y) & 0xFFFF0000u);
            u32 h1 = (__float_as_uint(v.z) >> 16) | (__float_as_uint(v.w) & 0xFFFF0000u);
            float lx = v.x - bfh(v.x), ly = v.y - bfh(v.y);
            float lz = v.z - bfh(v.z), lw = v.w - bfh(v.w);
            u32 e0 = (__float_as_uint(lx) >> 16) | (__float_as_uint(ly) & 0xFFFF0000u);
            u32 e1 = (__float_as_uint(lz) >> 16) | (__float_as_uint(lw) & 0xFFFF0000u);
            *(uint2*)(smem + TH_B + offTH((u32)srow, kbTH)) = make_uint2(h0, h1);
            *(uint2*)(smem + TL_B + (u32)(c & 1) * 16384u + offTL((u32)srow, kbTL)) = make_uint2(e0, e1);
            tsqp = fmaf(v.x, v.x, tsqp); tsqp = fmaf(v.y, v.y, tsqp);
            tsqp = fmaf(v.z, v.z, tsqp); tsqp = fmaf(v.w, v.w, tsqp);
        };

        // ---- prologue: stage chunk 0 ----
        {
            const float* rp = rbase;  // chunk 0
            float4 P0 = *(const float4*)(rp +   0);
            float4 P1 = *(const float4*)(rp + 128);
            float4 P2 = *(const float4*)(rp + 256);
            float4 P3 = *(const float4*)(rp + 384);
            cvw(P0, 0, 0); cvw(P1, 0, 1); cvw(P2, 0, 2); cvw(P3, 0, 3);
        }
        __syncthreads();

        f32x4 acc0 = {0.f, 0.f, 0.f, 0.f};
        f32x4 acc1 = {0.f, 0.f, 0.f, 0.f};

        for (int c = 0; c < NCHUNK; ++c) {
            float4 P0, P1, P2, P3;
            if (c < NCHUNK - 1) {   // issue next chunk's loads early (fly under compute)
                const float* rp = rbase + (c + 1) * KC;
                P0 = *(const float4*)(rp +   0);
                P1 = *(const float4*)(rp + 128);
                P2 = *(const float4*)(rp + 256);
                P3 = *(const float4*)(rp + 384);
            }
            // ---- phase A compute on chunk c: this wave's 64-k slice ----
#pragma unroll
            for (int ks = 0; ks < 2; ++ks) {
                const u32 kg = (u32)(c * KC + w * 64 + ks * 32 + q4 * 8);
                F8 ah0, ah1, al0, al1, bh, bl;
                ah0.u4 = *(const uint4*)(xh + (size_t)l15 * DIM + kg);
                ah1.u4 = *(const uint4*)(xh + (size_t)(l15 + 16) * DIM + kg);
                al0.u4 = *(const uint4*)(xl + (size_t)l15 * DIM + kg);
                al1.u4 = *(const uint4*)(xl + (size_t)(l15 + 16) * DIM + kg);
                bh.u4 = *(const uint4*)(smem + TH_B + offTH((u32)l15, kg * 2));
                bl.u4 = *(const uint4*)(smem + TL_B + (u32)(c & 1) * 16384u
                                        + offTL((u32)l15, (kg - c * KC) * 2));
                acc0 = __builtin_amdgcn_mfma_f32_16x16x32_bf16(ah0.bf, bh.bf, acc0, 0, 0, 0);
                acc0 = __builtin_amdgcn_mfma_f32_16x16x32_bf16(al0.bf, bh.bf, acc0, 0, 0, 0);
                acc0 = __builtin_amdgcn_mfma_f32_16x16x32_bf16(ah0.bf, bl.bf, acc0, 0, 0, 0);
                acc1 = __builtin_amdgcn_mfma_f32_16x16x32_bf16(ah1.bf, bh.bf, acc1, 0, 0, 0);
                acc1 = __builtin_amdgcn_mfma_f32_16x16x32_bf16(al1.bf, bh.bf, acc1, 0, 0, 0);
                acc1 = __builtin_amdgcn_mfma_f32_16x16x32_bf16(ah1.bf, bl.bf, acc1, 0, 0, 0);
            }
            if (c < NCHUNK - 1) {
                cvw(P0, c + 1, 0); cvw(P1, c + 1, 1); cvw(P2, c + 1, 2); cvw(P3, c + 1, 3);
            }
            __syncthreads();
        }

        // ---- cross-wave reduce of logits partials + tsq ----
#pragma unroll
        for (int r = 0; r < 4; ++r) {
            int b0 = q4 * 4 + r;
            *(float*)(smem + ARED_B + ((u32)(w * 512 + b0 * 16 + l15)) * 4u)        = acc0[r];
            *(float*)(smem + ARED_B + ((u32)(w * 512 + (b0 + 16) * 16 + l15)) * 4u) = acc1[r];
        }
        {
            float tq = tsqp;
            tq += __shfl_xor(tq, 1);  tq += __shfl_xor(tq, 2);
            tq += __shfl_xor(tq, 4);  tq += __shfl_xor(tq, 8);
            tq += __shfl_xor(tq, 16);
            if (sc == 0) *(float*)(smem + TSQ_B + (u32)srow * 4u) = tq;
        }
        __syncthreads();
        {
            int b = tid >> 4, j = tid & 15;
            float v = 0.0f;
#pragma unroll
            for (int wv_ = 0; wv_ < 8; ++wv_)
                v += *(const float*)(smem + ARED_B + ((u32)(wv_ * 512 + b * 16 + j)) * 4u);
            float lg = c1 * v - c2 * (*(const float*)(smem + TSQ_B + (u32)j * 4u));
            if (jbase + j >= jlim) lg = -3e38f;
            *(float*)(smem + LG_B + ((u32)(b * 17 + j)) * 4u) = lg;
        }
        __syncthreads();

        // ---- phase B: online softmax (each wave redundantly; lane owns b=l31) ----
        float wv[16];
        float pmax = -3e38f;
#pragma unroll
        for (int j = 0; j < 16; ++j) {
            wv[j] = *(const float*)(smem + LG_B + ((u32)(l31 * 17 + j)) * 4u);
            pmax = fmaxf(pmax, wv[j]);
        }
        const float nm   = fmaxf(m_run, pmax);
        const float corr = __expf(m_run - nm);
        float psum = 0.0f;
#pragma unroll
        for (int j = 0; j < 16; ++j) { wv[j] = __expf(wv[j] - nm); psum += wv[j]; }
        l_run = l_run * corr + psum;
        m_run = nm;
        *(float*)(smem + CORR_B + (u32)l31 * 4u) = corr;  // identical dup writes: benign

        float cr[16];
#pragma unroll
        for (int r = 0; r < 16; ++r) {
            int brow = (r & 3) + 8 * (r >> 2) + 4 * g32;
            cr[r] = *(const float*)(smem + CORR_B + (u32)brow * 4u);
        }
#pragma unroll
        for (int t0 = 0; t0 < NTILE; ++t0)
#pragma unroll
            for (int r = 0; r < 16; ++r) acc[t0][r] *= cr[r];

        F8 af;
#pragma unroll
        for (int e = 0; e < 8; ++e) {
            float we = g32 ? wv[8 + e] : wv[e];
            af.us[e] = bft(we);
        }

        // ---- phase C: PV from persistent th region (K = 16 j's) ----
#pragma unroll
        for (int t0 = 0; t0 < NTILE; ++t0) {
            const u32 d = (u32)(w * DPW + t0 * 32 + l31);
            F8 bfr;
#pragma unroll
            for (int e = 0; e < 8; ++e) {
                u32 j = (u32)(8 * g32 + e);
                bfr.us[e] = *(const u16*)(smem + TH_B + offTH(j, d * 2));
            }
            acc[t0] = __builtin_amdgcn_mfma_f32_32x32x16_bf16(af.bf, bfr.bf, acc[t0], 0, 0, 0);
        }
    }

    // ---- epilogue: write per-block partials + (m, l) ----
#pragma unroll
    for (int t0 = 0; t0 < NTILE; ++t0) {
        int d = w * DPW + t0 * 32 + l31;
#pragma unroll
        for (int r = 0; r < 16; ++r) {
            int brow = (r & 3) + 8 * (r >> 2) + 4 * g32;
            partial[((size_t)bid * BATCH + brow) * DIM + d] = acc[t0][r];
        }
    }
    if (tid < 32) {
        m_arr[bid * 32 + tid] = m_run;
        l_arr[bid * 32 + tid] = l_run;
    }
}

// ---------------- final: log-sum-exp merge of per-block partials ----------------
__global__ __launch_bounds__(256) void final_kernel(
        const float* __restrict__ x, const float* __restrict__ partial,
        const float* __restrict__ m_arr, const float* __restrict__ l_arr,
        const float* __restrict__ alphas, const int* __restrict__ tptr,
        float* __restrict__ out) {
    int i = blockIdx.x * 256 + threadIdx.x;
    if (i >= BATCH * DIM) return;
    int b = i / DIM;
    float ab = alphas[tptr[0]];
    float s  = sqrtf(ab);
    float om = 1.0f - ab;
    float inv = 1.0f / sqrtf(om);
    float M = -3e38f;
#pragma unroll 4
    for (int k = 0; k < NBLK; ++k) M = fmaxf(M, m_arr[k * 32 + b]);
    float L = 0.0f, wsum = 0.0f;
#pragma unroll 4
    for (int k = 0; k < NBLK; ++k) {
        float e = __expf(m_arr[k * 32 + b] - M);
        L    += l_arr[k * 32 + b] * e;
        wsum += partial[(size_t)k * (BATCH * DIM) + i] * e;
    }
    out[i] = inv * x[i] - s * inv * (wsum / L);
}

extern "C" void kernel_launch(void* const* d_in, const int* in_sizes, int n_in,
                              void* d_out, int out_size, void* d_ws, size_t ws_size,
                              hipStream_t stream) {
    const float* x      = (const float*)d_in[0];
    const float* train  = (const float*)d_in[1];
    const float* alphas = (const float*)d_in[2];
    const int*   tptr   = (const int*)d_in[3];
    float* out = (float*)d_out;

    char* ws = (char*)d_ws;
    float* partial = (float*)ws;                                   // 100,663,296 B
    float* m_arr   = (float*)(ws + 100663296);                     // 32,768 B
    float* l_arr   = (float*)(ws + 100663296 + 32768);             // 32,768 B
    u16*   xh      = (u16*)(ws + 100663296 + 65536);               // 196,608 B
    u16*   xl      = (u16*)(ws + 100663296 + 65536 + 196608);      // 196,608 B

    k0_split_x<<<(BATCH * DIM + 255) / 256, 256, 0, stream>>>(x, xh, xl);
    fused_kernel<<<NBLK, 512, 0, stream>>>(train, xh, xl, alphas, tptr,
                                           partial, m_arr, l_arr);
    final_kernel<<<(BATCH * DIM + 255) / 256, 256, 0, stream>>>(
        x, partial, m_arr, l_arr, alphas, tptr, out);
}

// Round 4
// 790.029 us; speedup vs baseline: 2.2876x; 2.2876x over previous
//
#include <hip/hip_runtime.h>

#define BATCH  32
#define DIM    3072
#define NTRAIN 100000
#define WROW   100352        /* wbuf padded row (mult of 16) */
#define SEGJ   12544         /* WROW / 8 */
#define SCH    98            /* j-chunks in PV pass */
#define JPC    1024          /* j per chunk */
#define DSPL   8             /* d-splits in PV pass (384 d each) */
#define NTILE  3             /* 32-col tiles per wave (3*32 = 96 d) */

typedef __bf16 bf16x8 __attribute__((ext_vector_type(8)));
typedef float  f32x16 __attribute__((ext_vector_type(16)));
typedef unsigned short u16;
typedef unsigned int   u32;

union F8 { u16 us[8]; uint4 u4; bf16x8 bf; };

__device__ __forceinline__ u16   bft(float f){ return (u16)(__float_as_uint(f) >> 16); }
__device__ __forceinline__ float bfh(float f){ return __uint_as_float(__float_as_uint(f) & 0xFFFF0000u); }
__device__ __forceinline__ float bfv(u16 h)  { return __uint_as_float(((u32)h) << 16); }

// ---------------- K0: split x into bf16 hi/lo ----------------
__global__ __launch_bounds__(256) void k0_split_x(
        const float* __restrict__ x, u16* __restrict__ xh, u16* __restrict__ xl) {
    int i = blockIdx.x * 256 + threadIdx.x;
    if (i >= BATCH * DIM) return;
    float f = x[i];
    xh[i] = bft(f);
    xl[i] = bft(f - bfh(f));
}

// ---------------- K1: logits[b][j] (proven round-1 structure) ----------------
__global__ __launch_bounds__(256) void k1_logits(
        const float* __restrict__ train,
        const u16* __restrict__ xh, const u16* __restrict__ xl,
        const float* __restrict__ alphas, const int* __restrict__ tptr,
        float* __restrict__ logits) {
    float ab = alphas[tptr[0]];
    float s  = sqrtf(ab);
    float om = 1.0f - ab;
    float c1 = s / om;
    float c2 = ab / (2.0f * om);

    int lane = threadIdx.x & 63;
    int wave = threadIdx.x >> 6;
    int l31  = lane & 31;
    int g    = lane >> 5;
    int j    = blockIdx.x * 128 + wave * 32 + l31;
    int jc   = j < NTRAIN ? j : (NTRAIN - 1);

    const float* trow = train + (size_t)jc * DIM;
    const u16* xhr = xh + l31 * DIM;
    const u16* xlr = xl + l31 * DIM;

    f32x16 acc;
#pragma unroll
    for (int r = 0; r < 16; ++r) acc[r] = 0.0f;
    float tsq = 0.0f;

    for (int kb = 0; kb < DIM; kb += 16) {
        int ko = kb + 8 * g;
        F8 ah, al, bh, bl;
        ah.u4 = *(const uint4*)(xhr + ko);
        al.u4 = *(const uint4*)(xlr + ko);
        float4 b0 = *(const float4*)(trow + ko);
        float4 b1 = *(const float4*)(trow + ko + 4);
        float bvv[8] = {b0.x, b0.y, b0.z, b0.w, b1.x, b1.y, b1.z, b1.w};
#pragma unroll
        for (int e = 0; e < 8; ++e) {
            float f = bvv[e];
            bh.us[e] = bft(f);
            bl.us[e] = bft(f - bfh(f));
            tsq = fmaf(f, f, tsq);
        }
        acc = __builtin_amdgcn_mfma_f32_32x32x16_bf16(ah.bf, bh.bf, acc, 0, 0, 0);
        acc = __builtin_amdgcn_mfma_f32_32x32x16_bf16(al.bf, bh.bf, acc, 0, 0, 0);
        acc = __builtin_amdgcn_mfma_f32_32x32x16_bf16(ah.bf, bl.bf, acc, 0, 0, 0);
    }
    tsq += __shfl_xor(tsq, 32, 64);   // two lane-halves covered disjoint k

    if (j < NTRAIN) {
#pragma unroll
        for (int r = 0; r < 16; ++r) {
            int brow = (r & 3) + 8 * (r >> 2) + 4 * g;
            logits[(size_t)brow * NTRAIN + j] = c1 * acc[r] - c2 * tsq;
        }
    }
}

// ---------------- K2a: row max ----------------
__global__ __launch_bounds__(1024) void k2a_rowmax(
        const float* __restrict__ logits, float* __restrict__ m) {
    int b = blockIdx.x;
    const float* row = logits + (size_t)b * NTRAIN;
    float mx = -3.0e38f;
    for (int i = threadIdx.x; i < NTRAIN; i += 1024) mx = fmaxf(mx, row[i]);
    __shared__ float red[1024];
    red[threadIdx.x] = mx;
    __syncthreads();
    for (int off = 512; off > 0; off >>= 1) {
        if (threadIdx.x < (unsigned)off)
            red[threadIdx.x] = fmaxf(red[threadIdx.x], red[threadIdx.x + off]);
        __syncthreads();
    }
    if (threadIdx.x == 0) m[b] = red[0];
}

// ---------------- K2b: weights = bf16(exp(logit - m)), padded; per-seg sums ----------------
__global__ __launch_bounds__(256) void k2b_expw(
        const float* __restrict__ logits, const float* __restrict__ m,
        u16* __restrict__ wbuf, float* __restrict__ lsum) {
    int blk = blockIdx.x;            // 256 = 32 b x 8 seg
    int b   = blk & 31;
    int seg = blk >> 5;
    float mb = m[b];
    int j0 = seg * SEGJ;
    float ls = 0.0f;
    for (int j = j0 + threadIdx.x; j < j0 + SEGJ; j += 256) {
        u16 wv = 0;
        if (j < NTRAIN) {
            float wf = __expf(logits[(size_t)b * NTRAIN + j] - mb);
            wv = bft(wf);
            ls += bfv(wv);           // denominator = sum of the weights PV actually uses
        }
        wbuf[(size_t)b * WROW + j] = wv;
    }
    __shared__ float red[256];
    red[threadIdx.x] = ls;
    __syncthreads();
    for (int off = 128; off > 0; off >>= 1) {
        if (threadIdx.x < (unsigned)off) red[threadIdx.x] += red[threadIdx.x + off];
        __syncthreads();
    }
    if (threadIdx.x == 0) lsum[seg * 32 + b] = red[0];
}

// ---------------- K3: PV pass — one coalesced train stream, no exp, no barriers ----------------
__global__ __launch_bounds__(256) void k3_pv(
        const float* __restrict__ train, const u16* __restrict__ wbuf,
        float* __restrict__ partial) {   // [SCH][BATCH][DIM]
    const int lane = threadIdx.x & 63;
    const int w    = threadIdx.x >> 6;
    const int l31  = lane & 31;
    const int g    = lane >> 5;
    const int ds   = blockIdx.x & (DSPL - 1);
    const int sc   = blockIdx.x / DSPL;
    const int dbase = ds * (DIM / DSPL) + w * (NTILE * 32);

    const u16* wrow = wbuf + (size_t)l31 * WROW;

    f32x16 acc[NTILE];
#pragma unroll
    for (int t = 0; t < NTILE; ++t)
#pragma unroll
        for (int r = 0; r < 16; ++r) acc[t][r] = 0.0f;

    const int jb0 = sc * JPC;

    if (sc < SCH - 1) {
        for (int ks = 0; ks < JPC / 16; ++ks) {
            const int jb = jb0 + ks * 16 + 8 * g;
            F8 af;
            af.u4 = *(const uint4*)(wrow + jb);
            const float* rp = train + (size_t)jb * DIM + dbase + l31;
            F8 bf0, bf1, bf2;
#pragma unroll
            for (int e = 0; e < 8; ++e) {
                const float* q = rp + e * DIM;
                bf0.us[e] = bft(q[0]);
                bf1.us[e] = bft(q[32]);
                bf2.us[e] = bft(q[64]);
            }
            acc[0] = __builtin_amdgcn_mfma_f32_32x32x16_bf16(af.bf, bf0.bf, acc[0], 0, 0, 0);
            acc[1] = __builtin_amdgcn_mfma_f32_32x32x16_bf16(af.bf, bf1.bf, acc[1], 0, 0, 0);
            acc[2] = __builtin_amdgcn_mfma_f32_32x32x16_bf16(af.bf, bf2.bf, acc[2], 0, 0, 0);
        }
    } else {
        for (int ks = 0; ks < JPC / 16; ++ks) {
            const int jb = jb0 + ks * 16 + 8 * g;
            F8 af;
            af.u4 = *(const uint4*)(wrow + jb);   // zeros beyond NTRAIN
            F8 bf0, bf1, bf2;
#pragma unroll
            for (int e = 0; e < 8; ++e) {
                int row = jb + e;
                row = row < NTRAIN ? row : (NTRAIN - 1);   // clamp: weight is 0 there
                const float* q = train + (size_t)row * DIM + dbase + l31;
                bf0.us[e] = bft(q[0]);
                bf1.us[e] = bft(q[32]);
                bf2.us[e] = bft(q[64]);
            }
            acc[0] = __builtin_amdgcn_mfma_f32_32x32x16_bf16(af.bf, bf0.bf, acc[0], 0, 0, 0);
            acc[1] = __builtin_amdgcn_mfma_f32_32x32x16_bf16(af.bf, bf1.bf, acc[1], 0, 0, 0);
            acc[2] = __builtin_amdgcn_mfma_f32_32x32x16_bf16(af.bf, bf2.bf, acc[2], 0, 0, 0);
        }
    }

#pragma unroll
    for (int t = 0; t < NTILE; ++t)
#pragma unroll
        for (int r = 0; r < 16; ++r) {
            int brow = (r & 3) + 8 * (r >> 2) + 4 * g;
            partial[((size_t)sc * BATCH + brow) * DIM + dbase + t * 32 + l31] = acc[t][r];
        }
}

// ---------------- K4: merge partials, scale, output ----------------
__global__ __launch_bounds__(256) void k4_final(
        const float* __restrict__ x, const float* __restrict__ partial,
        const float* __restrict__ lsum,
        const float* __restrict__ alphas, const int* __restrict__ tptr,
        float* __restrict__ out) {
    int i = blockIdx.x * 256 + threadIdx.x;
    if (i >= BATCH * DIM) return;
    int b = i / DIM;
    float ab  = alphas[tptr[0]];
    float s   = sqrtf(ab);
    float om  = 1.0f - ab;
    float inv = 1.0f / sqrtf(om);
    float L = 0.0f;
#pragma unroll
    for (int s2 = 0; s2 < 8; ++s2) L += lsum[s2 * 32 + b];
    float wsum = 0.0f;
#pragma unroll 4
    for (int c = 0; c < SCH; ++c)
        wsum += partial[(size_t)c * (BATCH * DIM) + i];
    out[i] = inv * x[i] - s * inv * (wsum / L);
}

extern "C" void kernel_launch(void* const* d_in, const int* in_sizes, int n_in,
                              void* d_out, int out_size, void* d_ws, size_t ws_size,
                              hipStream_t stream) {
    const float* x      = (const float*)d_in[0];
    const float* train  = (const float*)d_in[1];
    const float* alphas = (const float*)d_in[2];
    const int*   tptr   = (const int*)d_in[3];
    float* out = (float*)d_out;

    char* ws = (char*)d_ws;
    float* logits  = (float*)ws;                               // 12,800,000 B
    float* partial = (float*)(ws + 12800000);                  // 38,535,168 B
    u16*   wbuf    = (u16*)(ws + 12800000 + 38535168);         //  6,422,528 B
    float* m_arr   = (float*)(ws + 57757696);                  //        128 B
    float* lsum    = (float*)(ws + 57757824);                  //       1024 B
    u16*   xh      = (u16*)(ws + 57758848);                    //    196,608 B
    u16*   xl      = (u16*)(ws + 57955456);                    //    196,608 B

    k0_split_x<<<(BATCH * DIM + 255) / 256, 256, 0, stream>>>(x, xh, xl);
    k1_logits<<<(NTRAIN + 127) / 128, 256, 0, stream>>>(train, xh, xl, alphas, tptr, logits);
    k2a_rowmax<<<BATCH, 1024, 0, stream>>>(logits, m_arr);
    k2b_expw<<<256, 256, 0, stream>>>(logits, m_arr, wbuf, lsum);
    k3_pv<<<DSPL * SCH, 256, 0, stream>>>(train, wbuf, partial);
    k4_final<<<(BATCH * DIM + 255) / 256, 256, 0, stream>>>(x, partial, lsum, alphas, tptr, out);
}